// Round 1
// baseline (303.934 us; speedup 1.0000x reference)
//
#include <hip/hip_runtime.h>

#define EPSF 1e-20f

__device__ __forceinline__ float frcp(float x) { return __builtin_amdgcn_rcpf(x); }

// ---------------------------------------------------------------------------
// Normalized convolution, square input HxW = (1<<LOGHW)^2, stride 1, zero pad.
// One thread per output pixel; all COUT channels accumulated in registers.
// out = conv(x*c)/(conv(c)+eps) + b ; cout = conv(c)/sum(w)
// ---------------------------------------------------------------------------
template<int CIN, int COUT, int K, int PAD, int LOGHW>
__global__ __launch_bounds__(256)
void nconv_kern(const float* __restrict__ xin, const float* __restrict__ cin_,
                const float* __restrict__ wgt, const float* __restrict__ bias,
                float* __restrict__ xout, float* __restrict__ cout)
{
    constexpr int HW = 1 << LOGHW;
    constexpr int NW = COUT * CIN * K * K;
    __shared__ float s_w[NW];
    __shared__ float s_b[COUT];
    __shared__ float s_is[COUT];   // 1 / sum(w) per out channel
    const int tid = threadIdx.x;
    if (tid < NW)   s_w[tid] = wgt[tid];
    if (tid < COUT) s_b[tid] = bias[tid];
    __syncthreads();
    if (tid < COUT) {
        float s = 0.f;
        for (int i = 0; i < CIN * K * K; ++i) s += s_w[tid * CIN * K * K + i];
        s_is[tid] = 1.0f / s;
    }
    __syncthreads();

    const int idx = blockIdx.x * 256 + tid;
    const int w = idx & (HW - 1);
    const int h = (idx >> LOGHW) & (HW - 1);
    const int b = idx >> (2 * LOGHW);

    float denom[COUT], nomin[COUT];
    #pragma unroll
    for (int co = 0; co < COUT; ++co) { denom[co] = 0.f; nomin[co] = 0.f; }

    #pragma unroll
    for (int kh = 0; kh < K; ++kh) {
        const int hh = h + kh - PAD;
        const bool rok = (unsigned)hh < (unsigned)HW;
        const int hc = hh < 0 ? 0 : (hh >= HW ? HW - 1 : hh);
        #pragma unroll
        for (int kw = 0; kw < K; ++kw) {
            const int ww = w + kw - PAD;
            const bool ok = rok && ((unsigned)ww < (unsigned)HW);
            const int wc = ww < 0 ? 0 : (ww >= HW ? HW - 1 : ww);
            const int poff = hc * HW + wc;
            #pragma unroll
            for (int ci = 0; ci < CIN; ++ci) {
                const int a = ((b * CIN + ci) << (2 * LOGHW)) + poff;
                float cc = cin_[a];
                float xx = xin[a];
                cc = ok ? cc : 0.f;
                xx = ok ? xx : 0.f;
                const float dc = xx * cc;
                #pragma unroll
                for (int co = 0; co < COUT; ++co) {
                    const float wv = s_w[((co * CIN + ci) * K + kh) * K + kw];
                    denom[co] = fmaf(wv, cc, denom[co]);
                    nomin[co] = fmaf(wv, dc, nomin[co]);
                }
            }
        }
    }
    #pragma unroll
    for (int co = 0; co < COUT; ++co) {
        const int a = ((b * COUT + co) << (2 * LOGHW)) + h * HW + w;
        xout[a] = nomin[co] * frcp(denom[co] + EPSF) + s_b[co];
        cout[a] = denom[co] * s_is[co];
    }
}

// ---------------------------------------------------------------------------
// Decoder stage: nconv over concat(skip(2ch @full), up2(low(2ch @half))) with
// 3x3, pad 1, COUT=2. UP_FIRST selects channel order of the concat.
// Upsample is fused: low channels are read at (h>>1, w>>1).
// ---------------------------------------------------------------------------
template<bool UP_FIRST, int LOGHW>
__global__ __launch_bounds__(256)
void nconv_cat_kern(const float* __restrict__ skx, const float* __restrict__ skc,
                    const float* __restrict__ lox, const float* __restrict__ loc,
                    const float* __restrict__ wgt, const float* __restrict__ bias,
                    float* __restrict__ xout, float* __restrict__ cout)
{
    constexpr int HW = 1 << LOGHW;       // output (= skip) resolution
    constexpr int HWL = HW >> 1;         // low resolution
    constexpr int K = 3, PAD = 1, CIN = 4, COUT = 2;
    constexpr int NW = COUT * CIN * K * K;   // 72
    __shared__ float s_w[NW];
    __shared__ float s_b[COUT];
    __shared__ float s_is[COUT];
    const int tid = threadIdx.x;
    if (tid < NW)   s_w[tid] = wgt[tid];
    if (tid < COUT) s_b[tid] = bias[tid];
    __syncthreads();
    if (tid < COUT) {
        float s = 0.f;
        for (int i = 0; i < CIN * K * K; ++i) s += s_w[tid * CIN * K * K + i];
        s_is[tid] = 1.0f / s;
    }
    __syncthreads();

    const int idx = blockIdx.x * 256 + tid;
    const int w = idx & (HW - 1);
    const int h = (idx >> LOGHW) & (HW - 1);
    const int b = idx >> (2 * LOGHW);

    float denom[COUT], nomin[COUT];
    #pragma unroll
    for (int co = 0; co < COUT; ++co) { denom[co] = 0.f; nomin[co] = 0.f; }

    #pragma unroll
    for (int kh = 0; kh < K; ++kh) {
        const int hh = h + kh - PAD;
        const bool rok = (unsigned)hh < (unsigned)HW;
        const int hc = hh < 0 ? 0 : (hh >= HW ? HW - 1 : hh);
        #pragma unroll
        for (int kw = 0; kw < K; ++kw) {
            const int ww = w + kw - PAD;
            const bool ok = rok && ((unsigned)ww < (unsigned)HW);
            const int wc = ww < 0 ? 0 : (ww >= HW ? HW - 1 : ww);
            #pragma unroll
            for (int ci = 0; ci < CIN; ++ci) {
                const bool is_low = UP_FIRST ? (ci < 2) : (ci >= 2);
                const int lc = UP_FIRST ? (is_low ? ci : ci - 2)
                                        : (is_low ? ci - 2 : ci);
                float cc, xx;
                if (is_low) {
                    const int a = ((b * 2 + lc) << (2 * (LOGHW - 1)))
                                  + (hc >> 1) * HWL + (wc >> 1);
                    cc = loc[a];
                    xx = lox[a];
                } else {
                    const int a = ((b * 2 + lc) << (2 * LOGHW)) + hc * HW + wc;
                    cc = skc[a];
                    xx = skx[a];
                }
                cc = ok ? cc : 0.f;
                xx = ok ? xx : 0.f;
                const float dc = xx * cc;
                #pragma unroll
                for (int co = 0; co < COUT; ++co) {
                    const float wv = s_w[((co * CIN + ci) * K + kh) * K + kw];
                    denom[co] = fmaf(wv, cc, denom[co]);
                    nomin[co] = fmaf(wv, dc, nomin[co]);
                }
            }
        }
    }
    #pragma unroll
    for (int co = 0; co < COUT; ++co) {
        const int a = ((b * COUT + co) << (2 * LOGHW)) + h * HW + w;
        xout[a] = nomin[co] * frcp(denom[co] + EPSF) + s_b[co];
        cout[a] = denom[co] * s_is[co];
    }
}

// ---------------------------------------------------------------------------
// 2x2/stride-2 max pool on c (first-max tie-break, torch semantics),
// gathering x at argmax; c_out = max/4. Works on (B*C, H, W) flattened.
// ---------------------------------------------------------------------------
template<int LOGWO>
__global__ __launch_bounds__(256)
void maxpool_kern(const float* __restrict__ xi, const float* __restrict__ ci,
                  float* __restrict__ xo, float* __restrict__ co, int total)
{
    const int idx = blockIdx.x * 256 + threadIdx.x;
    if (idx >= total) return;
    constexpr int WO = 1 << LOGWO;
    constexpr int WI = WO * 2;
    const int wo = idx & (WO - 1);
    const int ho = (idx >> LOGWO) & (WO - 1);
    const int bc = idx >> (2 * LOGWO);
    const int base = (bc << (2 * (LOGWO + 1))) + (ho * 2) * WI + wo * 2;
    const float c00 = ci[base],       c01 = ci[base + 1];
    const float c10 = ci[base + WI],  c11 = ci[base + WI + 1];
    float best = c00; int bi = 0;
    if (c01 > best) { best = c01; bi = 1; }
    if (c10 > best) { best = c10; bi = 2; }
    if (c11 > best) { best = c11; bi = 3; }
    const int off = (bi >> 1) * WI + (bi & 1);
    xo[idx] = xi[base + off];
    co[idx] = best * 0.25f;
}

// ---------------------------------------------------------------------------
// Final 1x1 nconv (2ch -> 1ch), writes xout then cout flat into d_out.
// ---------------------------------------------------------------------------
__global__ __launch_bounds__(256)
void final_kern(const float* __restrict__ xin, const float* __restrict__ cin_,
                const float* __restrict__ w7, const float* __restrict__ b7,
                float* __restrict__ out, int npix)
{
    const int idx = blockIdx.x * 256 + threadIdx.x;
    if (idx >= npix) return;
    const int pix = idx & ((1 << 18) - 1);   // 512*512
    const int b = idx >> 18;
    const int a0 = ((b * 2 + 0) << 18) + pix;
    const int a1 = ((b * 2 + 1) << 18) + pix;
    const float w0 = w7[0], w1 = w7[1], bb = b7[0];
    const float c0v = cin_[a0], c1v = cin_[a1];
    const float x0v = xin[a0],  x1v = xin[a1];
    const float den = w0 * c0v + w1 * c1v;
    const float nom = w0 * x0v * c0v + w1 * x1v * c1v;
    out[idx] = nom * frcp(den + EPSF) + bb;
    out[npix + idx] = den * frcp(w0 + w1);
}

// ---------------------------------------------------------------------------
extern "C" void kernel_launch(void* const* d_in, const int* in_sizes, int n_in,
                              void* d_out, int out_size, void* d_ws, size_t ws_size,
                              hipStream_t stream) {
    (void)in_sizes; (void)n_in; (void)out_size; (void)ws_size;
    const float* x0 = (const float*)d_in[0];
    const float* c0 = (const float*)d_in[1];
    const float* w1 = (const float*)d_in[2];  const float* b1 = (const float*)d_in[3];
    const float* w2 = (const float*)d_in[4];  const float* b2 = (const float*)d_in[5];
    const float* w3 = (const float*)d_in[6];  const float* b3 = (const float*)d_in[7];
    const float* w4 = (const float*)d_in[8];  const float* b4 = (const float*)d_in[9];
    const float* w5 = (const float*)d_in[10]; const float* b5 = (const float*)d_in[11];
    const float* w6 = (const float*)d_in[12]; const float* b6 = (const float*)d_in[13];
    const float* w7 = (const float*)d_in[14]; const float* b7 = (const float*)d_in[15];

    float* ws = (float*)d_ws;
    const size_t S512 = 8ull * 2 * 512 * 512;   // 4,194,304 elems (2-ch tensor)
    const size_t S256 = 8ull * 2 * 256 * 256;
    const size_t S128 = 8ull * 2 * 128 * 128;
    const size_t S64  = 8ull * 2 * 64  * 64;

    // Persistent full-res skip (x1,c1):
    float* X1x = ws;            float* X1c = ws + S512;
    // Ping-pong full-res:
    float* Ax  = ws + 2 * S512; float* Ac  = ws + 3 * S512;
    float* Bx  = ws + 4 * S512; float* Bc  = ws + 5 * S512;
    // 256-res buffers overlay region A (dead after stage 2): 8*S256 == 2*S512
    float* x23x = Ax;               float* x23c = Ax + S256;
    float* x2x  = Ax + 2 * S256;    float* x2c  = Ax + 3 * S256;
    float* p1x  = Ax + 4 * S256;    float* p1c  = Ax + 5 * S256;
    float* qx   = Ax + 6 * S256;    float* qc   = Ax + 7 * S256;
    // 128/64-res buffers overlay region B (dead after stage 3):
    float* x3x  = Bx;               float* x3c  = Bx + S128;
    float* p2x  = Bx + 2 * S128;    float* p2c  = Bx + 3 * S128;
    float* x34x = Bx + 4 * S128;    float* x34c = Bx + 5 * S128;
    float* p3x  = Bx + 6 * S128;            float* p3c = Bx + 6 * S128 + S64;
    float* x4x  = Bx + 6 * S128 + 2 * S64;  float* x4c = Bx + 6 * S128 + 3 * S64;

    // Encoder @512
    nconv_kern<1, 2, 5, 2, 9><<<8192, 256, 0, stream>>>(x0, c0, w1, b1, Ax, Ac);
    nconv_kern<2, 2, 5, 2, 9><<<8192, 256, 0, stream>>>(Ax, Ac, w2, b2, Bx, Bc);
    nconv_kern<2, 2, 5, 2, 9><<<8192, 256, 0, stream>>>(Bx, Bc, w3, b3, X1x, X1c);
    // Pool to 256, encode
    maxpool_kern<8><<<4096, 256, 0, stream>>>(X1x, X1c, p1x, p1c, (int)S256);
    nconv_kern<2, 2, 5, 2, 8><<<2048, 256, 0, stream>>>(p1x, p1c, w2, b2, qx, qc);
    nconv_kern<2, 2, 5, 2, 8><<<2048, 256, 0, stream>>>(qx, qc, w3, b3, x2x, x2c);
    // Pool to 128, encode
    maxpool_kern<7><<<1024, 256, 0, stream>>>(x2x, x2c, p2x, p2c, (int)S128);
    nconv_kern<2, 2, 5, 2, 7><<<512, 256, 0, stream>>>(p2x, p2c, w2, b2, x3x, x3c);
    // Pool to 64, encode
    maxpool_kern<6><<<256, 256, 0, stream>>>(x3x, x3c, p3x, p3c, (int)S64);
    nconv_kern<2, 2, 5, 2, 6><<<128, 256, 0, stream>>>(p3x, p3c, w2, b2, x4x, x4c);
    // Decoder: concat(skip, up2(low)) for w4/w5; concat(up2(low), skip) for w6
    nconv_cat_kern<false, 7><<<512,  256, 0, stream>>>(x3x, x3c, x4x,  x4c,  w4, b4, x34x, x34c);
    nconv_cat_kern<false, 8><<<2048, 256, 0, stream>>>(x2x, x2c, x34x, x34c, w5, b5, x23x, x23c);
    nconv_cat_kern<true,  9><<<8192, 256, 0, stream>>>(X1x, X1c, x23x, x23c, w6, b6, Bx, Bc);
    // Final 1x1 -> d_out (xout flat, then cout flat)
    final_kern<<<8192, 256, 0, stream>>>(Bx, Bc, w7, b7, (float*)d_out, 8 * 512 * 512);
}

// Round 2
// 174.531 us; speedup vs baseline: 1.7414x; 1.7414x over previous
//
#include <hip/hip_runtime.h>

#define EPSF 1e-20f

__device__ __forceinline__ float frcp(float x) { return __builtin_amdgcn_rcpf(x); }

// ===========================================================================
// Pipeline runs in (U, c) representation, U = x*c.
//   nconv: denom = conv(c); nomin = conv(U); x = nomin/(denom+eps)+b;
//          c' = denom/sum(w); U' = x*c'.
//   maxpool (argmax over c, torch first-max): U' = U_sel/4, c' = c_max/4.
//   up2: replicate both U and c.
//   final 1x1: out = (w0*U0+w1*U1)/(w0*c0+w1*c1+eps)+b ; cout = den/(w0+w1).
// ===========================================================================

// ---------------------------------------------------------------------------
// Shared compute core: 2 out-channels x 4 horizontally-consecutive pixels.
// LDS tiles s_d (=conv numerator input) and s_c, layout [CIN][ROWS][72],
// covering global cols [base_w-4, base_w+68). Window for pixel group lw:
// 12 aligned floats [lw, lw+12) per (kh, ci); taps use j = p+kw+(4-PAD).
// ---------------------------------------------------------------------------
template<int CIN, int K, int ROWS>
__device__ __forceinline__ void conv_core(const float* __restrict__ s_d,
                                          const float* __restrict__ s_c,
                                          const float* __restrict__ wgt,
                                          int lh, int lw,
                                          float den[2][4], float nom[2][4])
{
    constexpr int JOFF = 4 - (K / 2);
    #pragma unroll
    for (int kh = 0; kh < K; ++kh) {
        #pragma unroll
        for (int ci = 0; ci < CIN; ++ci) {
            const float4* rd = (const float4*)(s_d + (ci * ROWS + lh + kh) * 72 + lw);
            const float4* rc = (const float4*)(s_c + (ci * ROWS + lh + kh) * 72 + lw);
            float wd[12], wc[12];
            #pragma unroll
            for (int q = 0; q < 3; ++q) {
                const float4 t = rd[q];
                wd[4*q+0] = t.x; wd[4*q+1] = t.y; wd[4*q+2] = t.z; wd[4*q+3] = t.w;
                const float4 u = rc[q];
                wc[4*q+0] = u.x; wc[4*q+1] = u.y; wc[4*q+2] = u.z; wc[4*q+3] = u.w;
            }
            #pragma unroll
            for (int kw = 0; kw < K; ++kw) {
                const float w0 = wgt[((0 * CIN + ci) * K + kh) * K + kw];
                const float w1 = wgt[((1 * CIN + ci) * K + kh) * K + kw];
                #pragma unroll
                for (int p = 0; p < 4; ++p) {
                    const int j = p + kw + JOFF;
                    den[0][p] = fmaf(w0, wc[j], den[0][p]);
                    nom[0][p] = fmaf(w0, wd[j], nom[0][p]);
                    den[1][p] = fmaf(w1, wc[j], den[1][p]);
                    nom[1][p] = fmaf(w1, wd[j], nom[1][p]);
                }
            }
        }
    }
}

template<int CIN, int K>
__device__ __forceinline__ void nconv_epilogue(const float* __restrict__ wgt,
                                               const float* __restrict__ bias,
                                               float den[2][4], float nom[2][4],
                                               float4 uo[2], float4 co4[2])
{
    #pragma unroll
    for (int c = 0; c < 2; ++c) {
        float s = 0.f;
        for (int i = 0; i < CIN * K * K; ++i) s += wgt[c * CIN * K * K + i];
        const float is = 1.0f / s;          // wave-uniform
        const float bb = bias[c];
        float u[4], cv[4];
        #pragma unroll
        for (int p = 0; p < 4; ++p) {
            const float xo = nom[c][p] * frcp(den[c][p] + EPSF) + bb;
            cv[p] = den[c][p] * is;
            u[p] = xo * cv[p];
        }
        uo[c]  = make_float4(u[0], u[1], u[2], u[3]);
        co4[c] = make_float4(cv[0], cv[1], cv[2], cv[3]);
    }
}

// ---------------------------------------------------------------------------
// Tiled normalized conv. Tile 64x16 out pixels, 256 threads, 4 px/thread.
// IN_IS_U: input tensors are (U, c); else (x, c) and d = x*c at staging.
// ---------------------------------------------------------------------------
template<int CIN, int K, int LOGHW, bool IN_IS_U>
__global__ __launch_bounds__(256)
void nconv_tiled(const float* __restrict__ xin, const float* __restrict__ cin_,
                 const float* __restrict__ wgt, const float* __restrict__ bias,
                 float* __restrict__ uout, float* __restrict__ cout)
{
    constexpr int HW = 1 << LOGHW;
    constexpr int PAD = K / 2;
    constexpr int TH = 16;
    constexpr int ROWS = TH + 2 * PAD;
    constexpr int NC4 = 18;
    __shared__ __align__(16) float s_d[CIN][ROWS][72];
    __shared__ __align__(16) float s_c[CIN][ROWS][72];

    const int tid = threadIdx.x;
    const int base_w = blockIdx.x * 64;
    const int base_h = blockIdx.y * TH;
    const int b = blockIdx.z;

    constexpr int SLOTS = CIN * ROWS * NC4;
    const float4* x4 = (const float4*)xin;
    const float4* c4p = (const float4*)cin_;
    for (int i = tid; i < SLOTS; i += 256) {
        const int ci = i / (ROWS * NC4);
        const int r  = (i / NC4) % ROWS;
        const int c4 = i % NC4;
        const int gh = base_h - PAD + r;
        const int gw4 = (base_w >> 2) + c4 - 1;
        float4 dd = make_float4(0.f, 0.f, 0.f, 0.f);
        float4 cc = make_float4(0.f, 0.f, 0.f, 0.f);
        if ((unsigned)gh < (unsigned)HW && (unsigned)gw4 < (unsigned)(HW >> 2)) {
            const int a = ((b * CIN + ci) << (2 * LOGHW - 2)) + (gh << (LOGHW - 2)) + gw4;
            const float4 xx = x4[a];
            cc = c4p[a];
            if (IN_IS_U) dd = xx;
            else dd = make_float4(xx.x * cc.x, xx.y * cc.y, xx.z * cc.z, xx.w * cc.w);
        }
        *(float4*)&s_d[ci][r][c4 * 4] = dd;
        *(float4*)&s_c[ci][r][c4 * 4] = cc;
    }
    __syncthreads();

    const int lh = tid >> 4;
    const int lw = (tid & 15) << 2;
    float den[2][4], nom[2][4];
    #pragma unroll
    for (int c = 0; c < 2; ++c)
        #pragma unroll
        for (int p = 0; p < 4; ++p) { den[c][p] = 0.f; nom[c][p] = 0.f; }

    conv_core<CIN, K, ROWS>(&s_d[0][0][0], &s_c[0][0][0], wgt, lh, lw, den, nom);

    float4 uo[2], co4[2];
    nconv_epilogue<CIN, K>(wgt, bias, den, nom, uo, co4);

    const int oh = base_h + lh;
    #pragma unroll
    for (int c = 0; c < 2; ++c) {
        const int a = ((b * 2 + c) << (2 * LOGHW - 2)) + (oh << (LOGHW - 2)) + ((base_w + lw) >> 2);
        ((float4*)uout)[a] = uo[c];
        ((float4*)cout)[a] = co4[c];
    }
}

// ---------------------------------------------------------------------------
// Decoder: nconv over concat(skip 2ch @full, up2(low 2ch @half)), 3x3 pad 1.
// UP_FIRST => concat order (up, skip). Low channels replicated at staging.
// ---------------------------------------------------------------------------
template<bool UP_FIRST, int LOGHW>
__global__ __launch_bounds__(256)
void nconv_cat_tiled(const float* __restrict__ skU, const float* __restrict__ skC,
                     const float* __restrict__ loU, const float* __restrict__ loC,
                     const float* __restrict__ wgt, const float* __restrict__ bias,
                     float* __restrict__ uout, float* __restrict__ cout)
{
    constexpr int HW = 1 << LOGHW;
    constexpr int K = 3, CIN = 4, TH = 16;
    constexpr int ROWS = TH + 2;
    constexpr int NC4 = 18;
    __shared__ __align__(16) float s_d[CIN][ROWS][72];
    __shared__ __align__(16) float s_c[CIN][ROWS][72];

    const int tid = threadIdx.x;
    const int base_w = blockIdx.x * 64;
    const int base_h = blockIdx.y * TH;
    const int b = blockIdx.z;

    constexpr int SLOTS = CIN * ROWS * NC4;
    const float4* sU4 = (const float4*)skU;
    const float4* sC4 = (const float4*)skC;
    for (int i = tid; i < SLOTS; i += 256) {
        const int ci = i / (ROWS * NC4);
        const int r  = (i / NC4) % ROWS;
        const int c4 = i % NC4;
        const int gh = base_h - 1 + r;
        const int gw4 = (base_w >> 2) + c4 - 1;
        float4 dd = make_float4(0.f, 0.f, 0.f, 0.f);
        float4 cc = make_float4(0.f, 0.f, 0.f, 0.f);
        if ((unsigned)gh < (unsigned)HW && (unsigned)gw4 < (unsigned)(HW >> 2)) {
            const bool is_low = UP_FIRST ? (ci < 2) : (ci >= 2);
            const int lc = is_low ? (UP_FIRST ? ci : ci - 2)
                                  : (UP_FIRST ? ci - 2 : ci);
            if (is_low) {
                const int ll = (gw4 * 4) >> 1;   // low col of slot start (even g_col)
                const int a = ((b * 2 + lc) << (2 * (LOGHW - 1))) + ((gh >> 1) << (LOGHW - 1)) + ll;
                const float u0 = loU[a], u1 = loU[a + 1];
                const float l0 = loC[a], l1 = loC[a + 1];
                dd = make_float4(u0, u0, u1, u1);
                cc = make_float4(l0, l0, l1, l1);
            } else {
                const int a = ((b * 2 + lc) << (2 * LOGHW - 2)) + (gh << (LOGHW - 2)) + gw4;
                dd = sU4[a];
                cc = sC4[a];
            }
        }
        *(float4*)&s_d[ci][r][c4 * 4] = dd;
        *(float4*)&s_c[ci][r][c4 * 4] = cc;
    }
    __syncthreads();

    const int lh = tid >> 4;
    const int lw = (tid & 15) << 2;
    float den[2][4], nom[2][4];
    #pragma unroll
    for (int c = 0; c < 2; ++c)
        #pragma unroll
        for (int p = 0; p < 4; ++p) { den[c][p] = 0.f; nom[c][p] = 0.f; }

    conv_core<CIN, K, ROWS>(&s_d[0][0][0], &s_c[0][0][0], wgt, lh, lw, den, nom);

    float4 uo[2], co4[2];
    nconv_epilogue<CIN, K>(wgt, bias, den, nom, uo, co4);

    const int oh = base_h + lh;
    #pragma unroll
    for (int c = 0; c < 2; ++c) {
        const int a = ((b * 2 + c) << (2 * LOGHW - 2)) + (oh << (LOGHW - 2)) + ((base_w + lw) >> 2);
        ((float4*)uout)[a] = uo[c];
        ((float4*)cout)[a] = co4[c];
    }
}

// ---------------------------------------------------------------------------
// 2x2/s2 maxpool on c (first-max), gather U; both scaled by 1/4.
// Each thread makes 2 output pixels from one float4-row-pair.
// ---------------------------------------------------------------------------
template<int LOGWO>
__global__ __launch_bounds__(256)
void maxpool_kern(const float* __restrict__ Ui, const float* __restrict__ Ci,
                  float* __restrict__ Uo, float* __restrict__ Co, int total2)
{
    const int t = blockIdx.x * 256 + threadIdx.x;
    if (t >= total2) return;
    constexpr int WO = 1 << LOGWO;
    const int wo2 = t & ((WO >> 1) - 1);
    const int ho  = (t >> (LOGWO - 1)) & (WO - 1);
    const int bc  = t >> (2 * LOGWO - 1);
    const int ib = (bc << (2 * LOGWO)) + (ho << LOGWO) + wo2;   // float4 idx
    const int rs = 1 << (LOGWO - 1);                            // row stride (f4)
    const float4* U4 = (const float4*)Ui;
    const float4* C4 = (const float4*)Ci;
    const float4 ct = C4[ib], cb = C4[ib + rs];
    const float4 ut = U4[ib], ub = U4[ib + rs];
    float m0 = ct.x, g0 = ut.x;
    if (ct.y > m0) { m0 = ct.y; g0 = ut.y; }
    if (cb.x > m0) { m0 = cb.x; g0 = ub.x; }
    if (cb.y > m0) { m0 = cb.y; g0 = ub.y; }
    float m1 = ct.z, g1 = ut.z;
    if (ct.w > m1) { m1 = ct.w; g1 = ut.w; }
    if (cb.z > m1) { m1 = cb.z; g1 = ub.z; }
    if (cb.w > m1) { m1 = cb.w; g1 = ub.w; }
    const int o2 = (bc << (2 * LOGWO - 1)) + (ho << (LOGWO - 1)) + wo2;  // float2 idx
    ((float2*)Uo)[o2] = make_float2(g0 * 0.25f, g1 * 0.25f);
    ((float2*)Co)[o2] = make_float2(m0 * 0.25f, m1 * 0.25f);
}

// ---------------------------------------------------------------------------
// Final 1x1 nconv (2ch -> 1ch) from (U, c); writes xout then cout flat.
// ---------------------------------------------------------------------------
__global__ __launch_bounds__(256)
void final_kern(const float* __restrict__ U, const float* __restrict__ C,
                const float* __restrict__ w7, const float* __restrict__ b7,
                float* __restrict__ out, int npix4)
{
    const int t = blockIdx.x * 256 + threadIdx.x;
    if (t >= npix4) return;
    const int pix4 = t & ((1 << 16) - 1);    // 512*512/4 per batch-channel
    const int b = t >> 16;
    const int a0 = ((b * 2) << 16) + pix4;
    const int a1 = a0 + (1 << 16);
    const float4* U4 = (const float4*)U;
    const float4* C4 = (const float4*)C;
    const float4 u0 = U4[a0], u1 = U4[a1], c0 = C4[a0], c1 = C4[a1];
    const float w0 = w7[0], w1 = w7[1], bb = b7[0];
    const float inv = frcp(w0 + w1);
    float4 xo, co;
    #pragma unroll
    for (int p = 0; p < 4; ++p) {
        const float cu0 = (&c0.x)[p], cu1 = (&c1.x)[p];
        const float uu0 = (&u0.x)[p], uu1 = (&u1.x)[p];
        const float den = w0 * cu0 + w1 * cu1;
        (&xo.x)[p] = (w0 * uu0 + w1 * uu1) * frcp(den + EPSF) + bb;
        (&co.x)[p] = den * inv;
    }
    ((float4*)out)[(b << 16) + pix4] = xo;
    ((float4*)out)[npix4 + (b << 16) + pix4] = co;
}

// ---------------------------------------------------------------------------
extern "C" void kernel_launch(void* const* d_in, const int* in_sizes, int n_in,
                              void* d_out, int out_size, void* d_ws, size_t ws_size,
                              hipStream_t stream) {
    (void)in_sizes; (void)n_in; (void)out_size; (void)ws_size;
    const float* x0 = (const float*)d_in[0];
    const float* c0 = (const float*)d_in[1];
    const float* w1 = (const float*)d_in[2];  const float* b1 = (const float*)d_in[3];
    const float* w2 = (const float*)d_in[4];  const float* b2 = (const float*)d_in[5];
    const float* w3 = (const float*)d_in[6];  const float* b3 = (const float*)d_in[7];
    const float* w4 = (const float*)d_in[8];  const float* b4 = (const float*)d_in[9];
    const float* w5 = (const float*)d_in[10]; const float* b5 = (const float*)d_in[11];
    const float* w6 = (const float*)d_in[12]; const float* b6 = (const float*)d_in[13];
    const float* w7 = (const float*)d_in[14]; const float* b7 = (const float*)d_in[15];

    float* ws = (float*)d_ws;
    const size_t S512 = 8ull * 2 * 512 * 512;
    const size_t S256 = 8ull * 2 * 256 * 256;
    const size_t S128 = 8ull * 2 * 128 * 128;
    const size_t S64  = 8ull * 2 * 64  * 64;

    // All buffers hold (U, c) pairs.
    float* X1x = ws;            float* X1c = ws + S512;
    float* Ax  = ws + 2 * S512; float* Ac  = ws + 3 * S512;
    float* Bx  = ws + 4 * S512; float* Bc  = ws + 5 * S512;
    float* x23x = Ax;               float* x23c = Ax + S256;
    float* x2x  = Ax + 2 * S256;    float* x2c  = Ax + 3 * S256;
    float* p1x  = Ax + 4 * S256;    float* p1c  = Ax + 5 * S256;
    float* qx   = Ax + 6 * S256;    float* qc   = Ax + 7 * S256;
    float* x3x  = Bx;               float* x3c  = Bx + S128;
    float* p2x  = Bx + 2 * S128;    float* p2c  = Bx + 3 * S128;
    float* x34x = Bx + 4 * S128;    float* x34c = Bx + 5 * S128;
    float* p3x  = Bx + 6 * S128;            float* p3c = Bx + 6 * S128 + S64;
    float* x4x  = Bx + 6 * S128 + 2 * S64;  float* x4c = Bx + 6 * S128 + 3 * S64;

    // Encoder @512
    nconv_tiled<1, 5, 9, false><<<dim3(8, 32, 8), 256, 0, stream>>>(x0, c0, w1, b1, Ax, Ac);
    nconv_tiled<2, 5, 9, true ><<<dim3(8, 32, 8), 256, 0, stream>>>(Ax, Ac, w2, b2, Bx, Bc);
    nconv_tiled<2, 5, 9, true ><<<dim3(8, 32, 8), 256, 0, stream>>>(Bx, Bc, w3, b3, X1x, X1c);
    // Pool to 256, encode
    maxpool_kern<8><<<2048, 256, 0, stream>>>(X1x, X1c, p1x, p1c, 524288);
    nconv_tiled<2, 5, 8, true><<<dim3(4, 16, 8), 256, 0, stream>>>(p1x, p1c, w2, b2, qx, qc);
    nconv_tiled<2, 5, 8, true><<<dim3(4, 16, 8), 256, 0, stream>>>(qx, qc, w3, b3, x2x, x2c);
    // Pool to 128, encode
    maxpool_kern<7><<<512, 256, 0, stream>>>(x2x, x2c, p2x, p2c, 131072);
    nconv_tiled<2, 5, 7, true><<<dim3(2, 8, 8), 256, 0, stream>>>(p2x, p2c, w2, b2, x3x, x3c);
    // Pool to 64, encode
    maxpool_kern<6><<<128, 256, 0, stream>>>(x3x, x3c, p3x, p3c, 32768);
    nconv_tiled<2, 5, 6, true><<<dim3(1, 4, 8), 256, 0, stream>>>(p3x, p3c, w2, b2, x4x, x4c);
    // Decoder
    nconv_cat_tiled<false, 7><<<dim3(2, 8, 8),  256, 0, stream>>>(x3x, x3c, x4x,  x4c,  w4, b4, x34x, x34c);
    nconv_cat_tiled<false, 8><<<dim3(4, 16, 8), 256, 0, stream>>>(x2x, x2c, x34x, x34c, w5, b5, x23x, x23c);
    nconv_cat_tiled<true,  9><<<dim3(8, 32, 8), 256, 0, stream>>>(X1x, X1c, x23x, x23c, w6, b6, Bx, Bc);
    // Final 1x1 -> d_out
    final_kern<<<2048, 256, 0, stream>>>(Bx, Bc, w7, b7, (float*)d_out, 524288);
}

// Round 3
// 144.292 us; speedup vs baseline: 2.1064x; 1.2096x over previous
//
#include <hip/hip_runtime.h>

#define EPSF 1e-20f

__device__ __forceinline__ float frcp(float x) { return __builtin_amdgcn_rcpf(x); }

// ===========================================================================
// Pipeline runs in (U, c) representation, U = x*c.
//   nconv: den = conv(c); nom = conv(U); x = nom/(den+eps)+b; c' = den/sum(w);
//          U' = x*c'.
//   maxpool (argmax over c, torch first-max): U' = U_sel/4, c' = c_max/4.
//   up2: replicate (fused as half-res reads).
//   final 1x1: out = (w0*U0+w1*U1)/(w0*c0+w1*c1+eps)+b ; cout = den/(w0+w1).
// ===========================================================================

// ---------------------------------------------------------------------------
// Conv core on full-res LDS tiles, row stride 72 floats, window 12 per row.
// NCI channels starting at weight-channel CI0, weight ci-stride CINT.
// ---------------------------------------------------------------------------
template<int NCI, int CI0, int CINT, int K, int ROWS>
__device__ __forceinline__ void conv_core(const float* __restrict__ s_d,
                                          const float* __restrict__ s_c,
                                          const float* __restrict__ wgt,
                                          int lh, int lw,
                                          float den[2][4], float nom[2][4])
{
    constexpr int JOFF = 4 - (K / 2);
    #pragma unroll
    for (int kh = 0; kh < K; ++kh) {
        #pragma unroll
        for (int ci = 0; ci < NCI; ++ci) {
            const float4* rd = (const float4*)(s_d + (ci * ROWS + lh + kh) * 72 + lw);
            const float4* rc = (const float4*)(s_c + (ci * ROWS + lh + kh) * 72 + lw);
            float wd[12], wc[12];
            #pragma unroll
            for (int q = 0; q < 3; ++q) {
                const float4 t = rd[q];
                wd[4*q] = t.x; wd[4*q+1] = t.y; wd[4*q+2] = t.z; wd[4*q+3] = t.w;
                const float4 u = rc[q];
                wc[4*q] = u.x; wc[4*q+1] = u.y; wc[4*q+2] = u.z; wc[4*q+3] = u.w;
            }
            #pragma unroll
            for (int kw = 0; kw < K; ++kw) {
                const float w0 = wgt[((0 * CINT + CI0 + ci) * K + kh) * K + kw];
                const float w1 = wgt[((1 * CINT + CI0 + ci) * K + kh) * K + kw];
                #pragma unroll
                for (int p = 0; p < 4; ++p) {
                    const int j = p + kw + JOFF;
                    den[0][p] = fmaf(w0, wc[j], den[0][p]);
                    nom[0][p] = fmaf(w0, wd[j], nom[0][p]);
                    den[1][p] = fmaf(w1, wc[j], den[1][p]);
                    nom[1][p] = fmaf(w1, wd[j], nom[1][p]);
                }
            }
        }
    }
}

// ---------------------------------------------------------------------------
// Conv over half-res (2x-replicated) LDS tiles [2][10][40]; K=3 only.
// Low tile origin: row (base_h/2 - 1), col (base_w/2 - 4).
// ---------------------------------------------------------------------------
template<int LO0>
__device__ __forceinline__ void conv_low(const float* __restrict__ s_lo_d,
                                         const float* __restrict__ s_lo_c,
                                         const float* __restrict__ wgt,
                                         int lh, int lw,
                                         float den[2][4], float nom[2][4])
{
    #pragma unroll
    for (int kh = 0; kh < 3; ++kh) {
        const int rel_r = ((lh + kh - 1) >> 1) + 1;   // arithmetic shift: -1>>1 = -1
        #pragma unroll
        for (int lci = 0; lci < 2; ++lci) {
            const float* rd = s_lo_d + (lci * 10 + rel_r) * 40 + (lw >> 1) + 2;
            const float* rc = s_lo_c + (lci * 10 + rel_r) * 40 + (lw >> 1) + 2;
            float wd[6], wc[6];
            #pragma unroll
            for (int q = 0; q < 3; ++q) {
                const float2 t = *(const float2*)(rd + 2 * q);
                wd[2*q] = t.x; wd[2*q+1] = t.y;
                const float2 u = *(const float2*)(rc + 2 * q);
                wc[2*q] = u.x; wc[2*q+1] = u.y;
            }
            #pragma unroll
            for (int kw = 0; kw < 3; ++kw) {
                const float w0 = wgt[((0 * 4 + LO0 + lci) * 3 + kh) * 3 + kw];
                const float w1 = wgt[((1 * 4 + LO0 + lci) * 3 + kh) * 3 + kw];
                #pragma unroll
                for (int p = 0; p < 4; ++p) {
                    const int t = p + kw - 1;
                    const int jl = ((t < 0) ? -1 : (t >> 1)) + 2;   // compile-time
                    den[0][p] = fmaf(w0, wc[jl], den[0][p]);
                    nom[0][p] = fmaf(w0, wd[jl], nom[0][p]);
                    den[1][p] = fmaf(w1, wc[jl], den[1][p]);
                    nom[1][p] = fmaf(w1, wd[jl], nom[1][p]);
                }
            }
        }
    }
}

template<int CINT, int K>
__device__ __forceinline__ void nconv_epilogue(const float* __restrict__ wgt,
                                               const float* __restrict__ bias,
                                               float den[2][4], float nom[2][4],
                                               float4 uo[2], float4 co4[2])
{
    #pragma unroll
    for (int c = 0; c < 2; ++c) {
        float s = 0.f;
        for (int i = 0; i < CINT * K * K; ++i) s += wgt[c * CINT * K * K + i];
        const float is = 1.0f / s;          // wave-uniform
        const float bb = bias[c];
        #pragma unroll
        for (int p = 0; p < 4; ++p) {
            const float xo = nom[c][p] * frcp(den[c][p] + EPSF) + bb;
            const float cv = den[c][p] * is;
            (&co4[c].x)[p] = cv;
            (&uo[c].x)[p]  = xo * cv;
        }
    }
}

// ---------------------------------------------------------------------------
// Tiled normalized conv, 64x16 out px, 256 threads, 4 px/thread.
// Optional fused 2x2 maxpool (first-max on c) producing half-res outputs.
// ---------------------------------------------------------------------------
template<int CIN, int K, int LOGHW, bool IN_IS_U, bool POOL>
__global__ __launch_bounds__(256)
void nconv_tiled(const float* __restrict__ xin, const float* __restrict__ cin_,
                 const float* __restrict__ wgt, const float* __restrict__ bias,
                 float* __restrict__ uout, float* __restrict__ cout,
                 float* __restrict__ poolU, float* __restrict__ poolC)
{
    constexpr int HW = 1 << LOGHW;
    constexpr int PAD = K / 2;
    constexpr int TH = 16;
    constexpr int ROWS = TH + 2 * PAD;
    constexpr int NC4 = 18;
    __shared__ __align__(16) float s_d[CIN][ROWS][72];
    __shared__ __align__(16) float s_c[CIN][ROWS][72];

    const int tid = threadIdx.x;
    const int base_w = blockIdx.x * 64;
    const int base_h = blockIdx.y * TH;
    const int b = blockIdx.z;

    constexpr int SLOTS = CIN * ROWS * NC4;
    const float4* x4 = (const float4*)xin;
    const float4* c4p = (const float4*)cin_;
    for (int i = tid; i < SLOTS; i += 256) {
        const int ci = i / (ROWS * NC4);
        const int r  = (i / NC4) % ROWS;
        const int cf = i % NC4;
        const int gh = base_h - PAD + r;
        const int gw4 = (base_w >> 2) + cf - 1;
        float4 dd = make_float4(0.f, 0.f, 0.f, 0.f);
        float4 cc = make_float4(0.f, 0.f, 0.f, 0.f);
        if ((unsigned)gh < (unsigned)HW && (unsigned)gw4 < (unsigned)(HW >> 2)) {
            const int a = ((b * CIN + ci) << (2 * LOGHW - 2)) + (gh << (LOGHW - 2)) + gw4;
            const float4 xx = x4[a];
            cc = c4p[a];
            if (IN_IS_U) dd = xx;
            else dd = make_float4(xx.x * cc.x, xx.y * cc.y, xx.z * cc.z, xx.w * cc.w);
        }
        *(float4*)&s_d[ci][r][cf * 4] = dd;
        *(float4*)&s_c[ci][r][cf * 4] = cc;
    }
    __syncthreads();

    const int lh = tid >> 4;
    const int lw = (tid & 15) << 2;
    float den[2][4], nom[2][4];
    #pragma unroll
    for (int c = 0; c < 2; ++c)
        #pragma unroll
        for (int p = 0; p < 4; ++p) { den[c][p] = 0.f; nom[c][p] = 0.f; }

    conv_core<CIN, 0, CIN, K, ROWS>(&s_d[0][0][0], &s_c[0][0][0], wgt, lh, lw, den, nom);

    float4 uo[2], co4[2];
    nconv_epilogue<CIN, K>(wgt, bias, den, nom, uo, co4);

    const int oh = base_h + lh;
    #pragma unroll
    for (int c = 0; c < 2; ++c) {
        const int a = ((b * 2 + c) << (2 * LOGHW - 2)) + (oh << (LOGHW - 2)) + ((base_w + lw) >> 2);
        ((float4*)uout)[a] = uo[c];
        ((float4*)cout)[a] = co4[c];
    }

    if (POOL) {
        // Round-trip outputs through LDS (overlay on s_d/s_c) for 2x2 pooling.
        __syncthreads();
        float* pu = &s_d[0][0][0];   // [2][16][64]
        float* pcb = &s_c[0][0][0];
        #pragma unroll
        for (int c = 0; c < 2; ++c) {
            *(float4*)&pu[(c * 16 + lh) * 64 + lw] = uo[c];
            *(float4*)&pcb[(c * 16 + lh) * 64 + lw] = co4[c];
        }
        __syncthreads();
        #pragma unroll
        for (int rep = 0; rep < 2; ++rep) {
            const int o = tid + rep * 256;
            const int ch = o >> 8;
            const int idx = o & 255;
            const int pr = idx >> 5;
            const int pcc = idx & 31;
            const int bse = (ch * 16 + 2 * pr) * 64 + 2 * pcc;
            const float c00 = pcb[bse],      c01 = pcb[bse + 1];
            const float c10 = pcb[bse + 64], c11 = pcb[bse + 65];
            float m = c00; float g = pu[bse];
            if (c01 > m) { m = c01; g = pu[bse + 1]; }
            if (c10 > m) { m = c10; g = pu[bse + 64]; }
            if (c11 > m) { m = c11; g = pu[bse + 65]; }
            const int pa = ((b * 2 + ch) << (2 * (LOGHW - 1)))
                         + (((base_h >> 1) + pr) << (LOGHW - 1)) + (base_w >> 1) + pcc;
            poolU[pa] = g * 0.25f;
            poolC[pa] = m * 0.25f;
        }
    }
}

// ---------------------------------------------------------------------------
// Decoder: nconv over concat(skip 2ch @full, up2(low 2ch @half)), 3x3 pad 1.
// Low channels staged at HALF resolution ([2][10][40] tiles). Optional fused
// final 1x1 nconv writing d_out (xout flat then cout flat).
// ---------------------------------------------------------------------------
template<bool UP_FIRST, int LOGHW, bool FINAL>
__global__ __launch_bounds__(256)
void nconv_cat_tiled(const float* __restrict__ skU, const float* __restrict__ skC,
                     const float* __restrict__ loU, const float* __restrict__ loC,
                     const float* __restrict__ wgt, const float* __restrict__ bias,
                     float* __restrict__ uout, float* __restrict__ cout,
                     const float* __restrict__ w7, const float* __restrict__ b7)
{
    constexpr int HW = 1 << LOGHW;
    constexpr int HWL = HW >> 1;
    constexpr int TH = 16;
    constexpr int ROWS = TH + 2;
    constexpr int NC4 = 18;
    constexpr int SK0 = UP_FIRST ? 2 : 0;   // skip channels' index in weights
    constexpr int LO0 = UP_FIRST ? 0 : 2;   // low channels' index in weights
    __shared__ __align__(16) float s_d[2][ROWS][72];
    __shared__ __align__(16) float s_c[2][ROWS][72];
    __shared__ __align__(16) float s_lo_d[2][10][40];
    __shared__ __align__(16) float s_lo_c[2][10][40];

    const int tid = threadIdx.x;
    const int base_w = blockIdx.x * 64;
    const int base_h = blockIdx.y * TH;
    const int b = blockIdx.z;

    // Stage skip channels (full res)
    constexpr int SLOTS = 2 * ROWS * NC4;
    const float4* sU4 = (const float4*)skU;
    const float4* sC4 = (const float4*)skC;
    for (int i = tid; i < SLOTS; i += 256) {
        const int ci = i / (ROWS * NC4);
        const int r  = (i / NC4) % ROWS;
        const int cf = i % NC4;
        const int gh = base_h - 1 + r;
        const int gw4 = (base_w >> 2) + cf - 1;
        float4 dd = make_float4(0.f, 0.f, 0.f, 0.f);
        float4 cc = make_float4(0.f, 0.f, 0.f, 0.f);
        if ((unsigned)gh < (unsigned)HW && (unsigned)gw4 < (unsigned)(HW >> 2)) {
            const int a = ((b * 2 + ci) << (2 * LOGHW - 2)) + (gh << (LOGHW - 2)) + gw4;
            dd = sU4[a];
            cc = sC4[a];
        }
        *(float4*)&s_d[ci][r][cf * 4] = dd;
        *(float4*)&s_c[ci][r][cf * 4] = cc;
    }
    // Stage low channels (half res): origin row base_h/2-1, col base_w/2-4
    constexpr int LO_SLOTS = 2 * 10 * 10;
    const int lo_r0 = (base_h >> 1) - 1;
    const int lo_c4_0 = (base_w >> 3) - 1;
    const float4* lU4 = (const float4*)loU;
    const float4* lC4 = (const float4*)loC;
    for (int i = tid; i < LO_SLOTS; i += 256) {
        const int ci = i / 100;
        const int r  = (i / 10) % 10;
        const int cf = i % 10;
        const int gr = lo_r0 + r;
        const int gc4 = lo_c4_0 + cf;
        float4 dd = make_float4(0.f, 0.f, 0.f, 0.f);
        float4 cc = make_float4(0.f, 0.f, 0.f, 0.f);
        if ((unsigned)gr < (unsigned)HWL && (unsigned)gc4 < (unsigned)(HWL >> 2)) {
            const int a = ((b * 2 + ci) << (2 * (LOGHW - 1) - 2)) + (gr << (LOGHW - 3)) + gc4;
            dd = lU4[a];
            cc = lC4[a];
        }
        *(float4*)&s_lo_d[ci][r][cf * 4] = dd;
        *(float4*)&s_lo_c[ci][r][cf * 4] = cc;
    }
    __syncthreads();

    const int lh = tid >> 4;
    const int lw = (tid & 15) << 2;
    float den[2][4], nom[2][4];
    #pragma unroll
    for (int c = 0; c < 2; ++c)
        #pragma unroll
        for (int p = 0; p < 4; ++p) { den[c][p] = 0.f; nom[c][p] = 0.f; }

    conv_core<2, SK0, 4, 3, ROWS>(&s_d[0][0][0], &s_c[0][0][0], wgt, lh, lw, den, nom);
    conv_low<LO0>(&s_lo_d[0][0][0], &s_lo_c[0][0][0], wgt, lh, lw, den, nom);

    float4 uo[2], co4[2];
    nconv_epilogue<4, 3>(wgt, bias, den, nom, uo, co4);

    const int oh = base_h + lh;
    if (FINAL) {
        const float w70 = w7[0], w71 = w7[1], bb7 = b7[0];
        const float inv = frcp(w70 + w71);
        float4 xo4, cc4;
        #pragma unroll
        for (int p = 0; p < 4; ++p) {
            const float d1 = w70 * (&co4[0].x)[p] + w71 * (&co4[1].x)[p];
            (&xo4.x)[p] = (w70 * (&uo[0].x)[p] + w71 * (&uo[1].x)[p]) * frcp(d1 + EPSF) + bb7;
            (&cc4.x)[p] = d1 * inv;
        }
        const int a = (b << (2 * LOGHW - 2)) + (oh << (LOGHW - 2)) + ((base_w + lw) >> 2);
        ((float4*)uout)[a] = xo4;
        ((float4*)uout)[(1 << 19) + a] = cc4;   // cout offset = 8*512*512/4
    } else {
        #pragma unroll
        for (int c = 0; c < 2; ++c) {
            const int a = ((b * 2 + c) << (2 * LOGHW - 2)) + (oh << (LOGHW - 2)) + ((base_w + lw) >> 2);
            ((float4*)uout)[a] = uo[c];
            ((float4*)cout)[a] = co4[c];
        }
    }
}

// ---------------------------------------------------------------------------
extern "C" void kernel_launch(void* const* d_in, const int* in_sizes, int n_in,
                              void* d_out, int out_size, void* d_ws, size_t ws_size,
                              hipStream_t stream) {
    (void)in_sizes; (void)n_in; (void)out_size; (void)ws_size;
    const float* x0 = (const float*)d_in[0];
    const float* c0 = (const float*)d_in[1];
    const float* w1 = (const float*)d_in[2];  const float* b1 = (const float*)d_in[3];
    const float* w2 = (const float*)d_in[4];  const float* b2 = (const float*)d_in[5];
    const float* w3 = (const float*)d_in[6];  const float* b3 = (const float*)d_in[7];
    const float* w4 = (const float*)d_in[8];  const float* b4 = (const float*)d_in[9];
    const float* w5 = (const float*)d_in[10]; const float* b5 = (const float*)d_in[11];
    const float* w6 = (const float*)d_in[12]; const float* b6 = (const float*)d_in[13];
    const float* w7 = (const float*)d_in[14]; const float* b7 = (const float*)d_in[15];

    float* ws = (float*)d_ws;
    const size_t S512 = 8ull * 2 * 512 * 512;
    const size_t S256 = 8ull * 2 * 256 * 256;
    const size_t S128 = 8ull * 2 * 128 * 128;
    const size_t S64  = 8ull * 2 * 64  * 64;

    // All buffers hold (U, c) pairs.
    float* X1x = ws;            float* X1c = ws + S512;
    float* Ax  = ws + 2 * S512; float* Ac  = ws + 3 * S512;
    float* Bx  = ws + 4 * S512; float* Bc  = ws + 5 * S512;
    float* x23x = Ax;               float* x23c = Ax + S256;
    float* x2x  = Ax + 2 * S256;    float* x2c  = Ax + 3 * S256;
    float* p1x  = Ax + 4 * S256;    float* p1c  = Ax + 5 * S256;
    float* qx   = Ax + 6 * S256;    float* qc   = Ax + 7 * S256;
    float* x3x  = Bx;               float* x3c  = Bx + S128;
    float* p2x  = Bx + 2 * S128;    float* p2c  = Bx + 3 * S128;
    float* x34x = Bx + 4 * S128;    float* x34c = Bx + 5 * S128;
    float* p3x  = Bx + 6 * S128;            float* p3c = Bx + 6 * S128 + S64;
    float* x4x  = Bx + 6 * S128 + 2 * S64;  float* x4c = Bx + 6 * S128 + 3 * S64;

    // Encoder @512 (stage 3 fuses pool -> p1 @256)
    nconv_tiled<1, 5, 9, false, false><<<dim3(8, 32, 8), 256, 0, stream>>>(x0, c0, w1, b1, Ax, Ac, nullptr, nullptr);
    nconv_tiled<2, 5, 9, true,  false><<<dim3(8, 32, 8), 256, 0, stream>>>(Ax, Ac, w2, b2, Bx, Bc, nullptr, nullptr);
    nconv_tiled<2, 5, 9, true,  true ><<<dim3(8, 32, 8), 256, 0, stream>>>(Bx, Bc, w3, b3, X1x, X1c, p1x, p1c);
    // @256 (stage 5 fuses pool -> p2 @128)
    nconv_tiled<2, 5, 8, true,  false><<<dim3(4, 16, 8), 256, 0, stream>>>(p1x, p1c, w2, b2, qx, qc, nullptr, nullptr);
    nconv_tiled<2, 5, 8, true,  true ><<<dim3(4, 16, 8), 256, 0, stream>>>(qx, qc, w3, b3, x2x, x2c, p2x, p2c);
    // @128 (fuses pool -> p3 @64)
    nconv_tiled<2, 5, 7, true,  true ><<<dim3(2, 8, 8), 256, 0, stream>>>(p2x, p2c, w2, b2, x3x, x3c, p3x, p3c);
    // @64
    nconv_tiled<2, 5, 6, true,  false><<<dim3(1, 4, 8), 256, 0, stream>>>(p3x, p3c, w2, b2, x4x, x4c, nullptr, nullptr);
    // Decoder
    nconv_cat_tiled<false, 7, false><<<dim3(2, 8, 8),  256, 0, stream>>>(x3x, x3c, x4x,  x4c,  w4, b4, x34x, x34c, nullptr, nullptr);
    nconv_cat_tiled<false, 8, false><<<dim3(4, 16, 8), 256, 0, stream>>>(x2x, x2c, x34x, x34c, w5, b5, x23x, x23c, nullptr, nullptr);
    // Last decoder stage fused with final 1x1 -> d_out
    nconv_cat_tiled<true,  9, true ><<<dim3(8, 32, 8), 256, 0, stream>>>(X1x, X1c, x23x, x23c, w6, b6, (float*)d_out, nullptr, w7, b7);
}